// Round 6
// baseline (167.170 us; speedup 1.0000x reference)
//
#include <hip/hip_runtime.h>

#define EMBED 128
#define NEG 5
#define ROWS_PER_BLOCK 32   // 16 groups x 2 rows each, 256 threads

// ---------------------------------------------------------------------------
// Kernel 1: stream both tables sequentially to pull them into the Infinity
// Cache at streaming HBM efficiency (~6.3 TB/s) instead of letting the gather
// kernel fault them in at random-access efficiency (~2.7 TB/s). The harness
// poisons 268 MB of d_ws before every timed call, which flushes the 256 MB
// LLC — so this warm pass is needed every iteration.
// ---------------------------------------------------------------------------
__global__ __launch_bounds__(256) void warm_kernel(
    const float4* __restrict__ w4,   // w_table as float4, n4 elements
    const float4* __restrict__ v4,   // v_table as float4, n4 elements
    float* __restrict__ sink,        // d_ws, one float per block
    int n4)
{
    const int stride = gridDim.x * blockDim.x;
    float acc = 0.0f;
    for (int i = blockIdx.x * blockDim.x + threadIdx.x; i < n4; i += stride) {
        float4 a = w4[i];
        float4 b = v4[i];
        acc += a.x + a.y + a.z + a.w + b.x + b.y + b.z + b.w;
    }
    // Keep the loads alive: reduce within wave, one store per wave to d_ws.
    #pragma unroll
    for (int m = 32; m >= 1; m >>= 1) acc += __shfl_xor(acc, m, 64);
    if ((threadIdx.x & 63) == 0)
        sink[blockIdx.x * 4 + (threadIdx.x >> 6)] = acc;
}

// ---------------------------------------------------------------------------
// Kernel 2: the gather+dot+log-sigmoid kernel (R4 structure: 2 rows per
// 16-lane group, 2048 blocks -> full wave occupancy available).
// ---------------------------------------------------------------------------
__device__ __forceinline__ float dot8(float4 w0, float4 w1, float4 a0, float4 a1) {
    float s = w0.x * a0.x;
    s = fmaf(w0.y, a0.y, s);
    s = fmaf(w0.z, a0.z, s);
    s = fmaf(w0.w, a0.w, s);
    s = fmaf(w1.x, a1.x, s);
    s = fmaf(w1.y, a1.y, s);
    s = fmaf(w1.z, a1.z, s);
    s = fmaf(w1.w, a1.w, s);
    return s;
}

__global__ __launch_bounds__(256) void sgneg_kernel(
    const int* __restrict__ pos_w,
    const int* __restrict__ pos_v,
    const int* __restrict__ neg_v,
    const float* __restrict__ w_table,
    const float* __restrict__ v_table,
    float* __restrict__ out,
    int batch)
{
    const int tid = threadIdx.x;
    const int lane16 = tid & 15;
    const int grp = tid >> 4;

    __shared__ float scores[6 * ROWS_PER_BLOCK];  // [k][row], k-major
    __shared__ float wsum[4];

    const int bA = blockIdx.x * ROWS_PER_BLOCK + grp * 2;
    const int bB = bA + 1;
    const int bAc = bA < batch ? bA : batch - 1;
    const int bBc = bB < batch ? bB : batch - 1;

    // ---- index epoch ----
    const int iwA  = pos_w[bAc];
    const int ipvA = pos_v[bAc];
    const int nA0 = neg_v[bAc * NEG + 0];
    const int nA1 = neg_v[bAc * NEG + 1];
    const int nA2 = neg_v[bAc * NEG + 2];
    const int nA3 = neg_v[bAc * NEG + 3];
    const int nA4 = neg_v[bAc * NEG + 4];
    const int iwB  = pos_w[bBc];
    const int ipvB = pos_v[bBc];
    const int nB0 = neg_v[bBc * NEG + 0];
    const int nB1 = neg_v[bBc * NEG + 1];
    const int nB2 = neg_v[bBc * NEG + 2];
    const int nB3 = neg_v[bBc * NEG + 3];
    const int nB4 = neg_v[bBc * NEG + 4];

    const size_t o0 = (size_t)lane16 * 4;
    const size_t o1 = o0 + 64;

    const float* wrA = w_table + (size_t)iwA  * EMBED;
    const float* prA = v_table + (size_t)ipvA * EMBED;
    const float* rA0 = v_table + (size_t)nA0  * EMBED;
    const float* rA1 = v_table + (size_t)nA1  * EMBED;
    const float* rA2 = v_table + (size_t)nA2  * EMBED;
    const float* rA3 = v_table + (size_t)nA3  * EMBED;
    const float* rA4 = v_table + (size_t)nA4  * EMBED;
    const float* wrB = w_table + (size_t)iwB  * EMBED;
    const float* prB = v_table + (size_t)ipvB * EMBED;
    const float* rB0 = v_table + (size_t)nB0  * EMBED;
    const float* rB1 = v_table + (size_t)nB1  * EMBED;
    const float* rB2 = v_table + (size_t)nB2  * EMBED;
    const float* rB3 = v_table + (size_t)nB3  * EMBED;
    const float* rB4 = v_table + (size_t)nB4  * EMBED;

    // ---- gather epoch: all 28 float4 loads issued before any consumption ----
    const float4 Aw0 = *reinterpret_cast<const float4*>(wrA + o0);
    const float4 Aw1 = *reinterpret_cast<const float4*>(wrA + o1);
    const float4 Ap0 = *reinterpret_cast<const float4*>(prA + o0);
    const float4 Ap1 = *reinterpret_cast<const float4*>(prA + o1);
    const float4 Aa0 = *reinterpret_cast<const float4*>(rA0 + o0);
    const float4 Aa1 = *reinterpret_cast<const float4*>(rA0 + o1);
    const float4 Ab0 = *reinterpret_cast<const float4*>(rA1 + o0);
    const float4 Ab1 = *reinterpret_cast<const float4*>(rA1 + o1);
    const float4 Ac0 = *reinterpret_cast<const float4*>(rA2 + o0);
    const float4 Ac1 = *reinterpret_cast<const float4*>(rA2 + o1);
    const float4 Ae0 = *reinterpret_cast<const float4*>(rA3 + o0);
    const float4 Ae1 = *reinterpret_cast<const float4*>(rA3 + o1);
    const float4 Af0 = *reinterpret_cast<const float4*>(rA4 + o0);
    const float4 Af1 = *reinterpret_cast<const float4*>(rA4 + o1);

    const float4 Bw0 = *reinterpret_cast<const float4*>(wrB + o0);
    const float4 Bw1 = *reinterpret_cast<const float4*>(wrB + o1);
    const float4 Bp0 = *reinterpret_cast<const float4*>(prB + o0);
    const float4 Bp1 = *reinterpret_cast<const float4*>(prB + o1);
    const float4 Ba0 = *reinterpret_cast<const float4*>(rB0 + o0);
    const float4 Ba1 = *reinterpret_cast<const float4*>(rB0 + o1);
    const float4 Bb0 = *reinterpret_cast<const float4*>(rB1 + o0);
    const float4 Bb1 = *reinterpret_cast<const float4*>(rB1 + o1);
    const float4 Bc0 = *reinterpret_cast<const float4*>(rB2 + o0);
    const float4 Bc1 = *reinterpret_cast<const float4*>(rB2 + o1);
    const float4 Be0 = *reinterpret_cast<const float4*>(rB3 + o0);
    const float4 Be1 = *reinterpret_cast<const float4*>(rB3 + o1);
    const float4 Bf0 = *reinterpret_cast<const float4*>(rB4 + o0);
    const float4 Bf1 = *reinterpret_cast<const float4*>(rB4 + o1);

    float dA0 = dot8(Aw0, Aw1, Ap0, Ap1);
    float dA1 = dot8(Aw0, Aw1, Aa0, Aa1);
    float dA2 = dot8(Aw0, Aw1, Ab0, Ab1);
    float dA3 = dot8(Aw0, Aw1, Ac0, Ac1);
    float dA4 = dot8(Aw0, Aw1, Ae0, Ae1);
    float dA5 = dot8(Aw0, Aw1, Af0, Af1);
    float dB0 = dot8(Bw0, Bw1, Bp0, Bp1);
    float dB1 = dot8(Bw0, Bw1, Ba0, Ba1);
    float dB2 = dot8(Bw0, Bw1, Bb0, Bb1);
    float dB3 = dot8(Bw0, Bw1, Bc0, Bc1);
    float dB4 = dot8(Bw0, Bw1, Be0, Be1);
    float dB5 = dot8(Bw0, Bw1, Bf0, Bf1);

    #pragma unroll
    for (int m = 8; m >= 1; m >>= 1) {
        dA0 += __shfl_xor(dA0, m, 64);
        dA1 += __shfl_xor(dA1, m, 64);
        dA2 += __shfl_xor(dA2, m, 64);
        dA3 += __shfl_xor(dA3, m, 64);
        dA4 += __shfl_xor(dA4, m, 64);
        dA5 += __shfl_xor(dA5, m, 64);
        dB0 += __shfl_xor(dB0, m, 64);
        dB1 += __shfl_xor(dB1, m, 64);
        dB2 += __shfl_xor(dB2, m, 64);
        dB3 += __shfl_xor(dB3, m, 64);
        dB4 += __shfl_xor(dB4, m, 64);
        dB5 += __shfl_xor(dB5, m, 64);
    }

    if (lane16 == 0) {
        const int rowA = grp * 2;
        scores[0 * ROWS_PER_BLOCK + rowA] = dA0;
        scores[1 * ROWS_PER_BLOCK + rowA] = dA1;
        scores[2 * ROWS_PER_BLOCK + rowA] = dA2;
        scores[3 * ROWS_PER_BLOCK + rowA] = dA3;
        scores[4 * ROWS_PER_BLOCK + rowA] = dA4;
        scores[5 * ROWS_PER_BLOCK + rowA] = dA5;
        scores[0 * ROWS_PER_BLOCK + rowA + 1] = dB0;
        scores[1 * ROWS_PER_BLOCK + rowA + 1] = dB1;
        scores[2 * ROWS_PER_BLOCK + rowA + 1] = dB2;
        scores[3 * ROWS_PER_BLOCK + rowA + 1] = dB3;
        scores[4 * ROWS_PER_BLOCK + rowA + 1] = dB4;
        scores[5 * ROWS_PER_BLOCK + rowA + 1] = dB5;
    }
    __syncthreads();

    float t = 0.0f;
    if (tid < 6 * ROWS_PER_BLOCK) {
        const int k = tid >> 5;
        const int r = tid & 31;
        const int gb = blockIdx.x * ROWS_PER_BLOCK + r;
        if (gb < batch) {
            float s = scores[tid];
            s = fminf(10.0f, fmaxf(-10.0f, s));
            const float arg = (k == 0) ? -s : s;
            t = __logf(1.0f + __expf(arg));
        }
    }

    #pragma unroll
    for (int m = 32; m >= 1; m >>= 1) t += __shfl_xor(t, m, 64);
    if ((tid & 63) == 0) wsum[tid >> 6] = t;
    __syncthreads();
    if (tid == 0) atomicAdd(out, wsum[0] + wsum[1] + wsum[2] + wsum[3]);
}

extern "C" void kernel_launch(void* const* d_in, const int* in_sizes, int n_in,
                              void* d_out, int out_size, void* d_ws, size_t ws_size,
                              hipStream_t stream) {
    const int*   pos_w   = (const int*)d_in[0];
    const int*   pos_v   = (const int*)d_in[1];
    const int*   neg_v   = (const int*)d_in[2];
    const float* w_table = (const float*)d_in[3];
    const float* v_table = (const float*)d_in[4];
    float* out = (float*)d_out;

    const int batch = in_sizes[0];
    const int table_elems = in_sizes[3];           // 100000*128
    const int n4 = table_elems / 4;                // float4 count per table

    // d_out is poisoned to 0xAA before every timed launch — zero it.
    hipMemsetAsync(out, 0, sizeof(float), stream);

    // Warm pass: pull both tables into LLC at streaming efficiency.
    warm_kernel<<<2048, 256, 0, stream>>>(
        (const float4*)w_table, (const float4*)v_table, (float*)d_ws, n4);

    const int blocks = (batch + ROWS_PER_BLOCK - 1) / ROWS_PER_BLOCK;  // 2048
    sgneg_kernel<<<blocks, 256, 0, stream>>>(pos_w, pos_v, neg_v,
                                             w_table, v_table, out, batch);
}

// Round 7
// 141.060 us; speedup vs baseline: 1.1851x; 1.1851x over previous
//
#include <hip/hip_runtime.h>

#define EMBED 128
#define NEG 5
#define RPG 4                      // rows per 16-lane group
#define ROWS_PER_BLOCK 64          // 16 groups * RPG

// Roofline note (R2-R6 evidence): this kernel is bound by the L2-miss
// service rate for random 512B row gathers (~2.7 TB/s), invariant under
// per-wave MLP scaling (R5 null) and LLC pre-warming (R6 null).
// dur ≈ FETCH_SIZE / 2.7 TB/s, with FETCH (110 MB) within 1.5x of the
// unique-row byte floor (~75 MB). Config below is the measured best
// (41.3 us steady-state).
__global__ __launch_bounds__(256, 4) void sgneg_kernel(
    const int* __restrict__ pos_w,
    const int* __restrict__ pos_v,
    const int* __restrict__ neg_v,
    const float* __restrict__ w_table,
    const float* __restrict__ v_table,
    float* __restrict__ out,
    int batch)
{
    const int tid = threadIdx.x;
    const int lane16 = tid & 15;
    const int grp = tid >> 4;

    __shared__ float scores[6 * ROWS_PER_BLOCK];   // [k][row], k-major
    __shared__ float wsum[4];

    const size_t o0 = (size_t)lane16 * 4;
    const size_t o1 = o0 + 64;

    // ---- index epoch: all 7*RPG indices in one batch ----
    int idx[RPG][7];
    #pragma unroll
    for (int r = 0; r < RPG; ++r) {
        int b = blockIdx.x * ROWS_PER_BLOCK + grp * RPG + r;
        int bc = b < batch ? b : (batch - 1);
        idx[r][0] = pos_w[bc];
        idx[r][1] = pos_v[bc];
        idx[r][2] = neg_v[bc * NEG + 0];
        idx[r][3] = neg_v[bc * NEG + 1];
        idx[r][4] = neg_v[bc * NEG + 2];
        idx[r][5] = neg_v[bc * NEG + 3];
        idx[r][6] = neg_v[bc * NEG + 4];
    }

    // ---- gather epoch: 14*RPG float4 loads, all issued before consumption ----
    float4 lo[RPG][7], hi[RPG][7];
    #pragma unroll
    for (int r = 0; r < RPG; ++r) {
        #pragma unroll
        for (int j = 0; j < 7; ++j) {
            const float* base = (j == 0 ? w_table : v_table) + (size_t)idx[r][j] * EMBED;
            lo[r][j] = *reinterpret_cast<const float4*>(base + o0);
            hi[r][j] = *reinterpret_cast<const float4*>(base + o1);
        }
    }

    // ---- dots: d[r][k] = <w_r, v_rk> ----
    float d[RPG][6];
    #pragma unroll
    for (int r = 0; r < RPG; ++r) {
        #pragma unroll
        for (int k = 0; k < 6; ++k) {
            float4 w0 = lo[r][0], w1 = hi[r][0];
            float4 a0 = lo[r][k + 1], a1 = hi[r][k + 1];
            float s = w0.x * a0.x;
            s = fmaf(w0.y, a0.y, s);
            s = fmaf(w0.z, a0.z, s);
            s = fmaf(w0.w, a0.w, s);
            s = fmaf(w1.x, a1.x, s);
            s = fmaf(w1.y, a1.y, s);
            s = fmaf(w1.z, a1.z, s);
            s = fmaf(w1.w, a1.w, s);
            d[r][k] = s;
        }
    }

    // ---- butterfly reduce within each 16-lane group ----
    #pragma unroll
    for (int m = 8; m >= 1; m >>= 1) {
        #pragma unroll
        for (int r = 0; r < RPG; ++r) {
            #pragma unroll
            for (int k = 0; k < 6; ++k) {
                d[r][k] += __shfl_xor(d[r][k], m, 64);
            }
        }
    }

    if (lane16 == 0) {
        #pragma unroll
        for (int r = 0; r < RPG; ++r) {
            const int row = grp * RPG + r;
            #pragma unroll
            for (int k = 0; k < 6; ++k) {
                scores[k * ROWS_PER_BLOCK + row] = d[r][k];
            }
        }
    }
    __syncthreads();

    // ---- wave-parallel tail: 384 scores, each thread handles tid and tid+256 ----
    float t = 0.0f;
    #pragma unroll
    for (int pass = 0; pass < 2; ++pass) {
        const int i = tid + pass * 256;
        if (i < 6 * ROWS_PER_BLOCK) {
            const int k = i / ROWS_PER_BLOCK;
            const int r = i - k * ROWS_PER_BLOCK;
            const int gb = blockIdx.x * ROWS_PER_BLOCK + r;
            if (gb < batch) {
                float s = scores[i];
                s = fminf(10.0f, fmaxf(-10.0f, s));
                const float arg = (k == 0) ? -s : s;   // pos: log1p(e^-s); neg: log1p(e^s)
                t += __logf(1.0f + __expf(arg));       // fast HW exp/log; err << tolerance
            }
        }
    }

    // ---- block reduce: full-wave butterfly, then cross-wave via LDS ----
    #pragma unroll
    for (int m = 32; m >= 1; m >>= 1) t += __shfl_xor(t, m, 64);
    if ((tid & 63) == 0) wsum[tid >> 6] = t;
    __syncthreads();
    if (tid == 0) atomicAdd(out, wsum[0] + wsum[1] + wsum[2] + wsum[3]);
}

extern "C" void kernel_launch(void* const* d_in, const int* in_sizes, int n_in,
                              void* d_out, int out_size, void* d_ws, size_t ws_size,
                              hipStream_t stream) {
    const int*   pos_w   = (const int*)d_in[0];
    const int*   pos_v   = (const int*)d_in[1];
    const int*   neg_v   = (const int*)d_in[2];
    const float* w_table = (const float*)d_in[3];
    const float* v_table = (const float*)d_in[4];
    float* out = (float*)d_out;

    const int batch = in_sizes[0];

    // d_out is poisoned to 0xAA before every timed launch — zero it.
    hipMemsetAsync(out, 0, sizeof(float), stream);

    const int blocks = (batch + ROWS_PER_BLOCK - 1) / ROWS_PER_BLOCK;  // 1024
    sgneg_kernel<<<blocks, 256, 0, stream>>>(pos_w, pos_v, neg_v,
                                             w_table, v_table, out, batch);
}